// Round 9
// baseline (408.605 us; speedup 1.0000x reference)
//
#include <hip/hip_runtime.h>
#include <hip/hip_bf16.h>
#include <math.h>

#define LN_EPS 1e-5f

typedef short short8 __attribute__((ext_vector_type(8)));
typedef float floatx4 __attribute__((ext_vector_type(4)));

__device__ inline unsigned short f2bf(float f) {
    unsigned int u = __float_as_uint(f);
    u += 0x7fff + ((u >> 16) & 1);   // round-to-nearest-even
    return (unsigned short)(u >> 16);
}

__device__ inline void gl_lds16(const unsigned short* g, unsigned short* l) {
    __builtin_amdgcn_global_load_lds(
        (__attribute__((address_space(1))) const void*)g,
        (__attribute__((address_space(3))) void*)l, 16, 0, 0);
}

// overflow-safe tanh-approx GELU (max abs err ~1e-3 vs exact)
__device__ inline float gelu_f(float v) {
    float u2 = 2.0f * v * (0.7978845608f + 0.0356774081f * v * v);
    float t  = 1.0f - 2.0f / (__expf(u2) + 1.0f);
    return 0.5f * v * (1.0f + t);
}

#define CFENCE asm volatile("" ::: "memory")

// ---------------------------------------------------------------------------
// gemm8p: 256x256 bf16 MFMA GEMM — r4/r8 configuration (FFN1 95 µs, 739 TF;
// QK^T). BN=128 instantiations moved to gemm128 below (r9): occupancy theory
// — 1 block/CU leaves barrier stalls unfilled (m114 mechanism needs
// co-resident blocks); 128² tile at 64KB LDS gets 2 blocks/CU.
//  T1 XCD swizzle, T2 both-sides st_16x32, counted vmcnt(4), T5 setprio.
//  4 phases/K-tile, 16-MFMA clusters.
//  EPI: 2 = +bias, GELU, bf16 out;  3 = *scale + mask, bf16 out.
// ---------------------------------------------------------------------------
template<int EPI, int BN>
__global__ __launch_bounds__(512, 2) void gemm8p(
    const unsigned short* __restrict__ A, const unsigned short* __restrict__ B,
    const float* __restrict__ bias, const float* __restrict__ resid,
    void* __restrict__ Cptr,
    int M, int N, int K, long sA, long sB, long sC, long sBias, float scale)
{
    static_assert(BN == 256, "gemm8p: BN==256 only (BN=128 -> gemm128)");
    constexpr int WC = BN / 4;
    constexpr int NT = WC / 16;
    constexpr int NH = NT / 2;

    __shared__ alignas(16) unsigned short lds_a[2][2][256 * 32]; // 64 KB
    __shared__ alignas(16) unsigned short lds_b[2][2][BN * 32];  // 64 KB

    const int tid  = threadIdx.x;
    const int lane = tid & 63;
    const int wave = tid >> 6;
    const int quad = lane >> 4;
    const int l16  = lane & 15;
    const int wm = wave >> 2;
    const int wn = wave & 3;

    const int nwg = gridDim.x * gridDim.y * gridDim.z;
    int lin = blockIdx.x + gridDim.x * (blockIdx.y + gridDim.y * blockIdx.z);
    if ((nwg & 7) == 0) lin = (lin & 7) * (nwg >> 3) + (lin >> 3);
    const int bx = lin % gridDim.x;
    const int byz = lin / gridDim.x;
    const int by = byz % gridDim.y;
    const int bz = byz / gridDim.y;

    const int tile_m = by * 256;
    const int tile_n = bx * BN;
    const int batch  = bz;

    const unsigned short* Ab = A + (size_t)batch * sA;
    const unsigned short* Bb = B + (size_t)batch * sB;

    const int srow = tid >> 2;
    const int scs  = ((tid & 3) ^ ((tid & 32) ? 2 : 0)) * 8;
    const unsigned short* gA = Ab + (size_t)(tile_m + srow) * K + scs;
    const unsigned short* gB = Bb + (size_t)(tile_n + srow) * K + scs;
    const int ldst = tid * 8;

    const int kcs   = (quad * 8) ^ ((l16 & 8) << 1);
    const int abase = (wm * 128 + l16) * 32 + kcs;
    const int bbase = (wn * WC  + l16) * 32 + kcs;

    floatx4 acc[8][NT];
    const floatx4 zero = {0.f, 0.f, 0.f, 0.f};
#pragma unroll
    for (int i = 0; i < 8; i++)
#pragma unroll
        for (int j = 0; j < NT; j++) acc[i][j] = zero;

    auto stageA = [&](int buf, int h, int k0) {
        const unsigned short* s = gA + (size_t)h * 128 * K + k0;
        gl_lds16(s,      &lds_a[buf][0][h * 4096 + ldst]);
        gl_lds16(s + 32, &lds_a[buf][1][h * 4096 + ldst]);
    };
    auto stageB = [&](int buf, int h, int k0) {
        const unsigned short* s = gB + (size_t)h * 128 * K + k0;
        gl_lds16(s,      &lds_b[buf][0][h * 4096 + ldst]);
        gl_lds16(s + 32, &lds_b[buf][1][h * 4096 + ldst]);
    };

    const int nt = K >> 6;

    stageA(0, 0, 0); stageA(0, 1, 0);
    stageB(0, 0, 0); stageB(0, 1, 0);
    if (nt > 1) {
        stageB(1, 0, 64); stageB(1, 1, 64);
        asm volatile("s_waitcnt vmcnt(4)" ::: "memory");
    } else {
        asm volatile("s_waitcnt vmcnt(0)" ::: "memory");
    }
    __builtin_amdgcn_s_barrier(); CFENCE;

    int cur = 0;
    for (int t = 0; t < nt; ++t) {
        const int k0 = t * 64;
        short8 afr[4][2], bfrA[NH][2], bfrB[NH][2];

        // ========== P1: read A0 + B0 ; stage A(t+1, lo) ==========
#pragma unroll
        for (int i = 0; i < 4; i++)
#pragma unroll
            for (int kh = 0; kh < 2; kh++)
                afr[i][kh] = *(const short8*)&lds_a[cur][kh][abase + i * 512];
#pragma unroll
        for (int j = 0; j < NH; j++)
#pragma unroll
            for (int kh = 0; kh < 2; kh++)
                bfrA[j][kh] = *(const short8*)&lds_b[cur][kh][bbase + j * 512];
        if (t + 1 < nt) stageA(cur ^ 1, 0, k0 + 64);
        CFENCE; __builtin_amdgcn_s_barrier(); CFENCE;
        __builtin_amdgcn_s_setprio(1);
#pragma unroll
        for (int i = 0; i < 4; i++)
#pragma unroll
            for (int j = 0; j < NH; j++)
#pragma unroll
                for (int kh = 0; kh < 2; kh++)
                    acc[i][j] = __builtin_amdgcn_mfma_f32_16x16x32_bf16(
                        bfrA[j][kh], afr[i][kh], acc[i][j], 0, 0, 0);
        __builtin_amdgcn_s_setprio(0);
        CFENCE; __builtin_amdgcn_s_barrier(); CFENCE;

        // ========== P2: read B1 ; stage A(t+1, hi) ==========
#pragma unroll
        for (int j = 0; j < NH; j++)
#pragma unroll
            for (int kh = 0; kh < 2; kh++)
                bfrB[j][kh] = *(const short8*)&lds_b[cur][kh][bbase + (NH + j) * 512];
        if (t + 1 < nt) stageA(cur ^ 1, 1, k0 + 64);
        CFENCE; __builtin_amdgcn_s_barrier(); CFENCE;
        __builtin_amdgcn_s_setprio(1);
#pragma unroll
        for (int i = 0; i < 4; i++)
#pragma unroll
            for (int j = 0; j < NH; j++)
#pragma unroll
                for (int kh = 0; kh < 2; kh++)
                    acc[i][NH + j] = __builtin_amdgcn_mfma_f32_16x16x32_bf16(
                        bfrB[j][kh], afr[i][kh], acc[i][NH + j], 0, 0, 0);
        __builtin_amdgcn_s_setprio(0);
        CFENCE; __builtin_amdgcn_s_barrier(); CFENCE;

        // ========== P3: read A1 ; stage B(t+2, lo) ==========
#pragma unroll
        for (int i = 0; i < 4; i++)
#pragma unroll
            for (int kh = 0; kh < 2; kh++)
                afr[i][kh] = *(const short8*)&lds_a[cur][kh][abase + (4 + i) * 512];
        if (t + 2 < nt) stageB(cur, 0, k0 + 128);
        CFENCE; __builtin_amdgcn_s_barrier(); CFENCE;
        __builtin_amdgcn_s_setprio(1);
#pragma unroll
        for (int i = 0; i < 4; i++)
#pragma unroll
            for (int j = 0; j < NH; j++)
#pragma unroll
                for (int kh = 0; kh < 2; kh++)
                    acc[4 + i][NH + j] = __builtin_amdgcn_mfma_f32_16x16x32_bf16(
                        bfrB[j][kh], afr[i][kh], acc[4 + i][NH + j], 0, 0, 0);
        __builtin_amdgcn_s_setprio(0);
        CFENCE; __builtin_amdgcn_s_barrier(); CFENCE;

        // ========== P4: stage B(t+2, hi) ; MFMA from regs ; boundary ======
        if (t + 2 < nt) stageB(cur, 1, k0 + 128);
        __builtin_amdgcn_s_setprio(1);
#pragma unroll
        for (int i = 0; i < 4; i++)
#pragma unroll
            for (int j = 0; j < NH; j++)
#pragma unroll
                for (int kh = 0; kh < 2; kh++)
                    acc[4 + i][j] = __builtin_amdgcn_mfma_f32_16x16x32_bf16(
                        bfrA[j][kh], afr[i][kh], acc[4 + i][j], 0, 0, 0);
        __builtin_amdgcn_s_setprio(0);
        if (t + 3 <= nt) {
            asm volatile("s_waitcnt vmcnt(4)" ::: "memory");
            __builtin_amdgcn_s_barrier(); CFENCE;
        } else if (t + 2 == nt) {
            asm volatile("s_waitcnt vmcnt(0)" ::: "memory");
            __builtin_amdgcn_s_barrier(); CFENCE;
        }
        cur ^= 1;
    }

    // ---- epilogue ----
#pragma unroll
    for (int i = 0; i < 8; i++) {
        const int row = tile_m + wm * 128 + i * 16 + l16;
#pragma unroll
        for (int j = 0; j < NT; j++) {
            const int colb = tile_n + wn * WC + j * 16 + quad * 4;
            float v[4];
#pragma unroll
            for (int r = 0; r < 4; r++) v[r] = acc[i][j][r];

            if (EPI == 3) {
                float4 mv = *(const float4*)&bias[(size_t)batch * sBias + colb];
                v[0] = v[0] * scale + mv.x;  v[1] = v[1] * scale + mv.y;
                v[2] = v[2] * scale + mv.z;  v[3] = v[3] * scale + mv.w;
            }
            if (EPI == 2) {
                float4 bv = *(const float4*)&bias[colb];
                v[0] += bv.x; v[1] += bv.y; v[2] += bv.z; v[3] += bv.w;
#pragma unroll
                for (int r = 0; r < 4; r++) v[r] = gelu_f(v[r]);
            }

            unsigned short* C = (unsigned short*)Cptr + (size_t)batch * sC;
            ushort4 h4;
            h4.x = f2bf(v[0]); h4.y = f2bf(v[1]);
            h4.z = f2bf(v[2]); h4.w = f2bf(v[3]);
            *(ushort4*)(C + (size_t)row * N + colb) = h4;
        }
    }
}

// ---------------------------------------------------------------------------
// gemm128 (r9): 128x128 bf16 MFMA GEMM, 256 threads = 4 waves (2M x 2N),
// per-wave out 64x64. LDS 64 KB -> 2 blocks/CU RESIDENT (m97-class
// occupancy; m114: co-resident blocks fill each other's barrier stalls —
// the 1-block/CU BN=128 engine measured only ~474 TF on FFN2).
// Same verified levers: T1 XCD swizzle, T2 both-sides swizzle, 2-phase
// 16-MFMA clusters, counted vmcnt(4).
//  Schedule per K-tile:
//   P1: read afr[0..1]+ALL bfr (12 ds_read); stage A(t+1) [4 loads];
//       barrier; 16 MFMA; barrier  (B[cur] fully consumed -> dead)
//   P2: read afr[2..3] (4 ds_read); stage B(t+2) into B[cur] [4 loads];
//       16 MFMA; boundary vmcnt(4) [keeps B(t+2); retires A(t+1) and,
//       in-order, B(t+1) issued at t-1]; barrier.
//  Prologue: A0,B0,B1 (12 loads) -> vmcnt(4) retires A0+B0, keeps B1.
//  Edge: t+2==nt -> vmcnt(0); t+1==nt -> skip stageA.
//  EPI: 4 = +resid[batch], fp32 out (PV);  5 = +bias +resid, fp32 (FFN2).
//  M,N mult of 128; K mult of 128.
// ---------------------------------------------------------------------------
template<int EPI>
__global__ __launch_bounds__(256, 2) void gemm128(
    const unsigned short* __restrict__ A, const unsigned short* __restrict__ B,
    const float* __restrict__ bias, const float* __restrict__ resid,
    float* __restrict__ Cptr,
    int M, int N, int K, long sA, long sB, long sC, float scale)
{
    __shared__ alignas(16) unsigned short lds_a[2][2][128 * 32]; // 32 KB
    __shared__ alignas(16) unsigned short lds_b[2][2][128 * 32]; // 32 KB

    const int tid  = threadIdx.x;
    const int lane = tid & 63;
    const int wave = tid >> 6;         // 0..3
    const int quad = lane >> 4;
    const int l16  = lane & 15;
    const int wm = wave >> 1;          // 0..1 (64-row half)
    const int wn = wave & 1;           // 0..1 (64-col half)

    // T1 XCD swizzle
    const int nwg = gridDim.x * gridDim.y * gridDim.z;
    int lin = blockIdx.x + gridDim.x * (blockIdx.y + gridDim.y * blockIdx.z);
    if ((nwg & 7) == 0) lin = (lin & 7) * (nwg >> 3) + (lin >> 3);
    const int bx = lin % gridDim.x;
    const int byz = lin / gridDim.x;
    const int by = byz % gridDim.y;
    const int bz = byz / gridDim.y;

    const int tile_m = by * 128;
    const int tile_n = bx * 128;
    const int batch  = bz;

    const unsigned short* Ab = A + (size_t)batch * sA;
    const unsigned short* Bb = B + (size_t)batch * sB;

    // staging: 256 threads x 16B = 4KB/inst = one [64 rows][32 elems] region.
    // row = h*64 + (tid>>2); row&8 == (tid&32)>>2 -> same T2 source XOR.
    const int srow = tid >> 2;                                  // 0..63
    const int scs  = ((tid & 3) ^ ((tid & 32) ? 2 : 0)) * 8;
    const unsigned short* gA = Ab + (size_t)(tile_m + srow) * K + scs;
    const unsigned short* gB = Bb + (size_t)(tile_n + srow) * K + scs;
    const int ldst = tid * 8;                                   // elems

    const int kcs   = (quad * 8) ^ ((l16 & 8) << 1);
    const int abase = (wm * 64 + l16) * 32 + kcs;
    const int bbase = (wn * 64 + l16) * 32 + kcs;

    floatx4 acc[4][4];
    const floatx4 zero = {0.f, 0.f, 0.f, 0.f};
#pragma unroll
    for (int i = 0; i < 4; i++)
#pragma unroll
        for (int j = 0; j < 4; j++) acc[i][j] = zero;

    // one call stages a full 128x64 tile of A or B (4 gl_lds16)
    auto stageA = [&](int buf, int k0) {
#pragma unroll
        for (int h = 0; h < 2; h++) {
            const unsigned short* s = gA + (size_t)h * 64 * K + k0;
            gl_lds16(s,      &lds_a[buf][0][h * 2048 + ldst]);
            gl_lds16(s + 32, &lds_a[buf][1][h * 2048 + ldst]);
        }
    };
    auto stageB = [&](int buf, int k0) {
#pragma unroll
        for (int h = 0; h < 2; h++) {
            const unsigned short* s = gB + (size_t)h * 64 * K + k0;
            gl_lds16(s,      &lds_b[buf][0][h * 2048 + ldst]);
            gl_lds16(s + 32, &lds_b[buf][1][h * 2048 + ldst]);
        }
    };

    const int nt = K >> 6;

    // prologue: A0(4), B0(4), B1(4) -> vmcnt(4) retires A0+B0, keeps B1
    stageA(0, 0);
    stageB(0, 0);
    if (nt > 1) {
        stageB(1, 64);
        asm volatile("s_waitcnt vmcnt(4)" ::: "memory");
    } else {
        asm volatile("s_waitcnt vmcnt(0)" ::: "memory");
    }
    __builtin_amdgcn_s_barrier(); CFENCE;

    int cur = 0;
    for (int t = 0; t < nt; ++t) {
        const int k0 = t * 64;
        short8 afr[2][2], bfr[4][2];

        // ---- P1: read afr[0..1] + ALL bfr ; stage A(t+1) ----
#pragma unroll
        for (int i = 0; i < 2; i++)
#pragma unroll
            for (int kh = 0; kh < 2; kh++)
                afr[i][kh] = *(const short8*)&lds_a[cur][kh][abase + i * 512];
#pragma unroll
        for (int j = 0; j < 4; j++)
#pragma unroll
            for (int kh = 0; kh < 2; kh++)
                bfr[j][kh] = *(const short8*)&lds_b[cur][kh][bbase + j * 512];
        if (t + 1 < nt) stageA(cur ^ 1, k0 + 64);
        CFENCE; __builtin_amdgcn_s_barrier(); CFENCE;
        __builtin_amdgcn_s_setprio(1);
#pragma unroll
        for (int i = 0; i < 2; i++)
#pragma unroll
            for (int j = 0; j < 4; j++)
#pragma unroll
                for (int kh = 0; kh < 2; kh++)
                    acc[i][j] = __builtin_amdgcn_mfma_f32_16x16x32_bf16(
                        bfr[j][kh], afr[i][kh], acc[i][j], 0, 0, 0);
        __builtin_amdgcn_s_setprio(0);
        // end-P1 barrier: all waves' B reads complete -> B[cur] dead
        CFENCE; __builtin_amdgcn_s_barrier(); CFENCE;

        // ---- P2: read afr[2..3] ; stage B(t+2) over dead B[cur] ----
#pragma unroll
        for (int i = 0; i < 2; i++)
#pragma unroll
            for (int kh = 0; kh < 2; kh++)
                afr[i][kh] = *(const short8*)&lds_a[cur][kh][abase + (2 + i) * 512];
        if (t + 2 < nt) stageB(cur, k0 + 128);
        __builtin_amdgcn_s_setprio(1);
#pragma unroll
        for (int i = 0; i < 2; i++)
#pragma unroll
            for (int j = 0; j < 4; j++)
#pragma unroll
                for (int kh = 0; kh < 2; kh++)
                    acc[2 + i][j] = __builtin_amdgcn_mfma_f32_16x16x32_bf16(
                        bfr[j][kh], afr[i][kh], acc[2 + i][j], 0, 0, 0);
        __builtin_amdgcn_s_setprio(0);
        // boundary: outstanding = A(t+1)x4 + B(t+2)x4 -> vmcnt(4)
        if (t + 3 <= nt) {
            asm volatile("s_waitcnt vmcnt(4)" ::: "memory");
            __builtin_amdgcn_s_barrier(); CFENCE;
        } else if (t + 2 == nt) {
            asm volatile("s_waitcnt vmcnt(0)" ::: "memory");
            __builtin_amdgcn_s_barrier(); CFENCE;
        }
        cur ^= 1;
    }

    // ---- epilogue: fp32 out, +resid (EPI4) / +bias+resid (EPI5) ----
#pragma unroll
    for (int i = 0; i < 4; i++) {
        const int row = tile_m + wm * 64 + i * 16 + l16;
#pragma unroll
        for (int j = 0; j < 4; j++) {
            const int colb = tile_n + wn * 64 + j * 16 + quad * 4;
            float v[4];
#pragma unroll
            for (int r = 0; r < 4; r++) v[r] = acc[i][j][r];

            if (EPI == 5) {
                float4 bv = *(const float4*)&bias[colb];
                v[0] += bv.x; v[1] += bv.y; v[2] += bv.z; v[3] += bv.w;
            }
            float4 rv = *(const float4*)&resid[(size_t)batch * sC +
                                               (size_t)row * N + colb];
            v[0] += rv.x; v[1] += rv.y; v[2] += rv.z; v[3] += rv.w;

            float* C = Cptr + (size_t)batch * sC;
            float4 f4 = {v[0], v[1], v[2], v[3]};
            *(float4*)(C + (size_t)row * N + colb) = f4;
        }
    }
}

// ---------------------------------------------------------------------------
// x prep: read x [S,D] fp32 once -> xb [S,D] bf16 AND xTb [D,S] bf16.
// ---------------------------------------------------------------------------
__global__ __launch_bounds__(256) void x_prep_kernel(
    const float* __restrict__ in, unsigned short* __restrict__ straight,
    unsigned short* __restrict__ transposed, int R, int C, long sIn)
{
    __shared__ float tile[32][33];
    const int tc = blockIdx.x * 32, tr = blockIdx.y * 32;
    const float* src = in + (size_t)blockIdx.z * sIn;
    unsigned short* dstS = straight   + (size_t)blockIdx.z * sIn;
    unsigned short* dstT = transposed + (size_t)blockIdx.z * sIn;
    const int tx = threadIdx.x & 31, ty = threadIdx.x >> 5;
#pragma unroll
    for (int i = 0; i < 4; i++) {
        float val = src[(size_t)(tr + ty + i * 8) * C + tc + tx];
        tile[ty + i * 8][tx] = val;
        dstS[(size_t)(tr + ty + i * 8) * C + tc + tx] = f2bf(val);
    }
    __syncthreads();
#pragma unroll
    for (int i = 0; i < 4; i++)
        dstT[(size_t)(tc + ty + i * 8) * R + tr + tx] = f2bf(tile[tx][ty + i * 8]);
}

// ---------------------------------------------------------------------------
__global__ __launch_bounds__(256) void transpose_cvt_kernel(
    const float* __restrict__ in, unsigned short* __restrict__ out, int R, int C)
{
    __shared__ float tile[32][33];
    const int tc = blockIdx.x * 32, tr = blockIdx.y * 32;
    const int tx = threadIdx.x & 31, ty = threadIdx.x >> 5;
#pragma unroll
    for (int i = 0; i < 4; i++)
        tile[ty + i * 8][tx] = in[(size_t)(tr + ty + i * 8) * C + tc + tx];
    __syncthreads();
#pragma unroll
    for (int i = 0; i < 4; i++)
        out[(size_t)(tc + ty + i * 8) * R + tr + tx] = f2bf(tile[tx][ty + i * 8]);
}

// ---------------------------------------------------------------------------
// Pure row softmax over S=2048: bf16 in (scale+mask pre-applied) -> bf16 out.
// ---------------------------------------------------------------------------
__global__ __launch_bounds__(256) void softmax_bf16_kernel(
    const unsigned short* __restrict__ scores, unsigned short* __restrict__ probs,
    int S)
{
    __shared__ float red[4];
    const int row = blockIdx.x;
    const unsigned short* p = scores + (size_t)row * S;
    unsigned short* pr      = probs  + (size_t)row * S;
    const int tid  = threadIdx.x;
    const int lane = tid & 63;
    const int wav  = tid >> 6;

    uint4 raw = *(const uint4*)(p + tid * 8);   // 8 bf16
    float v[8];
    v[0] = __uint_as_float(raw.x << 16); v[1] = __uint_as_float(raw.x & 0xffff0000u);
    v[2] = __uint_as_float(raw.y << 16); v[3] = __uint_as_float(raw.y & 0xffff0000u);
    v[4] = __uint_as_float(raw.z << 16); v[5] = __uint_as_float(raw.z & 0xffff0000u);
    v[6] = __uint_as_float(raw.w << 16); v[7] = __uint_as_float(raw.w & 0xffff0000u);

    float mx = v[0];
#pragma unroll
    for (int k = 1; k < 8; k++) mx = fmaxf(mx, v[k]);
#pragma unroll
    for (int off = 32; off > 0; off >>= 1) mx = fmaxf(mx, __shfl_down(mx, off));
    if (lane == 0) red[wav] = mx;
    __syncthreads();
    mx = fmaxf(fmaxf(red[0], red[1]), fmaxf(red[2], red[3]));
    __syncthreads();

    float s = 0.f;
#pragma unroll
    for (int k = 0; k < 8; k++) { v[k] = __expf(v[k] - mx); s += v[k]; }
#pragma unroll
    for (int off = 32; off > 0; off >>= 1) s += __shfl_down(s, off);
    if (lane == 0) red[wav] = s;
    __syncthreads();
    s = red[0] + red[1] + red[2] + red[3];
    float inv = 1.0f / s;

    uint4 o;
    o.x = (unsigned)f2bf(v[0] * inv) | ((unsigned)f2bf(v[1] * inv) << 16);
    o.y = (unsigned)f2bf(v[2] * inv) | ((unsigned)f2bf(v[3] * inv) << 16);
    o.z = (unsigned)f2bf(v[4] * inv) | ((unsigned)f2bf(v[5] * inv) << 16);
    o.w = (unsigned)f2bf(v[6] * inv) | ((unsigned)f2bf(v[7] * inv) << 16);
    *(uint4*)(pr + tid * 8) = o;
}

// ---------------------------------------------------------------------------
// out_row = LayerNorm(X_row)*g + b.  D = 1024. In-place safe (out == X).
// ---------------------------------------------------------------------------
template<int WRITE_BF16>
__global__ __launch_bounds__(256) void ln_kernel(
    const float* __restrict__ X,
    const float* __restrict__ g, const float* __restrict__ bta,
    float* __restrict__ out, unsigned short* __restrict__ out16, int D)
{
    __shared__ float red[8];
    const int row = blockIdx.x;
    const float* x = X + (size_t)row * D;
    const int tid  = threadIdx.x;
    const int lane = tid & 63;
    const int wav  = tid >> 6;

    float4 a = *(const float4*)(x + tid * 4);
    float v0 = a.x, v1 = a.y, v2 = a.z, v3 = a.w;

    float s1 = v0 + v1 + v2 + v3;
    float s2 = v0 * v0 + v1 * v1 + v2 * v2 + v3 * v3;
#pragma unroll
    for (int off = 32; off > 0; off >>= 1) {
        s1 += __shfl_down(s1, off);
        s2 += __shfl_down(s2, off);
    }
    if (lane == 0) { red[wav] = s1; red[4 + wav] = s2; }
    __syncthreads();
    s1 = red[0] + red[1] + red[2] + red[3];
    s2 = red[4] + red[5] + red[6] + red[7];
    const float mu  = s1 / (float)D;
    const float var = s2 / (float)D - mu * mu;
    const float rs  = rsqrtf(var + LN_EPS);

    float4 gg = *(const float4*)(g + tid * 4);
    float4 bb = *(const float4*)(bta + tid * 4);
    float4 r;
    r.x = (v0 - mu) * rs * gg.x + bb.x;
    r.y = (v1 - mu) * rs * gg.y + bb.y;
    r.z = (v2 - mu) * rs * gg.z + bb.z;
    r.w = (v3 - mu) * rs * gg.w + bb.w;
    *(float4*)(out + (size_t)row * D + tid * 4) = r;
    if (WRITE_BF16) {
        ushort4 h;
        h.x = f2bf(r.x); h.y = f2bf(r.y); h.z = f2bf(r.z); h.w = f2bf(r.w);
        *(ushort4*)(out16 + (size_t)row * D + tid * 4) = h;
    }
}

// ---------------------------------------------------------------------------
extern "C" void kernel_launch(void* const* d_in, const int* in_sizes, int n_in,
                              void* d_out, int out_size, void* d_ws, size_t ws_size,
                              hipStream_t stream) {
    (void)in_sizes; (void)n_in; (void)out_size; (void)ws_size;
    const float* x    = (const float*)d_in[0];
    const float* mask = (const float*)d_in[1];
    const float* w1   = (const float*)d_in[2];
    const float* b1   = (const float*)d_in[3];
    const float* w2   = (const float*)d_in[4];
    const float* b2   = (const float*)d_in[5];
    const float* ln1g = (const float*)d_in[6];
    const float* ln1b = (const float*)d_in[7];
    const float* ln2g = (const float*)d_in[8];
    const float* ln2b = (const float*)d_in[9];
    float* out = (float*)d_out;

    const int B = 4, S = 2048, D = 1024, DFF = 4096;
    const size_t MB = 1024 * 1024;

    // ws (128 MiB):
    //  [0,32M):   scoresb bf16 (1-2)         } act bf16 [0,64M) (5-6)
    //  [32,64M):  xb bf16 [32,48M) (prep-1), then probs bf16 (2-3)
    //  [64,96M):  hbuf fp32 = h (3-6)
    //  [96,112M): hb16 bf16 (4-5)
    //  [112,120M): w1T   [120,128M): w2T
    // d_out (32 MiB): xTb [0,16M) (prep-3); then fsum fp32 = h+ffn (6-7), LN in place.
    char* ws = (char*)d_ws;
    unsigned short* scoresb = (unsigned short*)ws;
    unsigned short* act     = (unsigned short*)ws;
    unsigned short* xb      = (unsigned short*)(ws + 32 * MB);
    unsigned short* probs   = (unsigned short*)(ws + 32 * MB);
    float*          hbuf    = (float*)(ws + 64 * MB);
    unsigned short* hb16    = (unsigned short*)(ws + 96 * MB);
    unsigned short* w1T     = (unsigned short*)(ws + 112 * MB);
    unsigned short* w2T     = (unsigned short*)(ws + 120 * MB);
    unsigned short* xTb     = (unsigned short*)d_out;
    float*          fsum    = (float*)d_out;

    // --- prep ---
    x_prep_kernel<<<dim3(D / 32, S / 32, B), 256, 0, stream>>>(
        x, xb, xTb, S, D, (long)S * D);
    transpose_cvt_kernel<<<dim3(DFF / 32, D / 32, 1), 256, 0, stream>>>(w1, w1T, D, DFF);
    transpose_cvt_kernel<<<dim3(D / 32, DFF / 32, 1), 256, 0, stream>>>(w2, w2T, DFF, D);

    // 1. scoresb[b] = (xb[b] @ xb[b]^T)*scale + mask  -> bf16   (256 blocks)
    hipLaunchKernelGGL((gemm8p<3, 256>), dim3(S / 256, S / 256, B), dim3(512), 0, stream,
                       xb, xb, mask, (const float*)nullptr, (void*)scoresb,
                       S, S, D, (long)S * D, (long)S * D, (long)S * S, (long)S, 0.03125f);
    // 2. probs = softmax(scoresb) -> bf16
    softmax_bf16_kernel<<<B * S, 256, 0, stream>>>(scoresb, probs, S);
    // 3. hbuf[b] = x[b] + probs[b] @ xTb[b]^T  -> fp32
    //    r9: gemm128, grid (8,16,4)=512 blocks, 2 resident blocks/CU
    hipLaunchKernelGGL((gemm128<4>), dim3(D / 128, S / 128, B), dim3(256), 0, stream,
                       probs, xTb, (const float*)nullptr, x, hbuf,
                       S, D, S, (long)S * S, (long)D * S, (long)S * D, 0.f);
    // 4. h = LN(hbuf) in place + hb16 bf16
    hipLaunchKernelGGL((ln_kernel<1>), dim3(B * S), dim3(256), 0, stream,
                       hbuf, ln1g, ln1b, hbuf, hb16, D);
    // 5. act = gelu(h @ w1 + b1) -> bf16                        (512 blocks)
    hipLaunchKernelGGL((gemm8p<2, 256>), dim3(DFF / 256, (B * S) / 256, 1), dim3(512), 0, stream,
                       hb16, w1T, b1, (const float*)nullptr, (void*)act,
                       B * S, DFF, D, 0L, 0L, 0L, 0L, 0.f);
    // 6. fsum = h + act @ w2 + b2 -> fp32 (into d_out)
    //    r9: gemm128, grid (8,64,1)=512 blocks, 2 resident blocks/CU
    hipLaunchKernelGGL((gemm128<5>), dim3(D / 128, (B * S) / 128, 1), dim3(256), 0, stream,
                       act, w2T, b2, hbuf, fsum,
                       B * S, D, DFF, 0L, 0L, (long)0, 0.f);
    // 7. out = LN(fsum) in place
    hipLaunchKernelGGL((ln_kernel<0>), dim3(B * S), dim3(256), 0, stream,
                       fsum, ln2g, ln2b, out, (unsigned short*)nullptr, D);
}

// Round 10
// 401.151 us; speedup vs baseline: 1.0186x; 1.0186x over previous
//
#include <hip/hip_runtime.h>
#include <hip/hip_bf16.h>
#include <math.h>

#define LN_EPS 1e-5f

typedef short short8 __attribute__((ext_vector_type(8)));
typedef float floatx4 __attribute__((ext_vector_type(4)));

__device__ inline unsigned short f2bf(float f) {
    unsigned int u = __float_as_uint(f);
    u += 0x7fff + ((u >> 16) & 1);   // round-to-nearest-even
    return (unsigned short)(u >> 16);
}

__device__ inline float bf2f(unsigned short h) {
    return __uint_as_float((unsigned)h << 16);
}

__device__ inline void gl_lds16(const unsigned short* g, unsigned short* l) {
    __builtin_amdgcn_global_load_lds(
        (__attribute__((address_space(1))) const void*)g,
        (__attribute__((address_space(3))) void*)l, 16, 0, 0);
}

// overflow-safe tanh-approx GELU (max abs err ~1e-3 vs exact)
__device__ inline float gelu_f(float v) {
    float u2 = 2.0f * v * (0.7978845608f + 0.0356774081f * v * v);
    float t  = 1.0f - 2.0f / (__expf(u2) + 1.0f);
    return 0.5f * v * (1.0f + t);
}

#define CFENCE asm volatile("" ::: "memory")

// ---------------------------------------------------------------------------
// gemm8p: 256x256 bf16 MFMA GEMM — r4/r8 configuration (FFN1 93 µs, 739 TF =
// 87% of shape-matched m248 reference; QK^T). TEXTUALLY FROZEN since r8 —
// rule #19: changing this kernel's instantiation set re-rolled its codegen
// at -45% once (r7). BN=128 work lives in gemm128 (adding that kernel did
// NOT perturb FFN1 — r9 measured 93.1).
//  T1 XCD swizzle, T2 both-sides st_16x32, counted vmcnt(4), T5 setprio.
//  4 phases/K-tile, 16-MFMA clusters.
//  EPI: 2 = +bias, GELU, bf16 out;  3 = *scale + mask, bf16 out.
// ---------------------------------------------------------------------------
template<int EPI, int BN>
__global__ __launch_bounds__(512, 2) void gemm8p(
    const unsigned short* __restrict__ A, const unsigned short* __restrict__ B,
    const float* __restrict__ bias, const float* __restrict__ resid,
    void* __restrict__ Cptr,
    int M, int N, int K, long sA, long sB, long sC, long sBias, float scale)
{
    static_assert(BN == 256, "gemm8p: BN==256 only (BN=128 -> gemm128)");
    constexpr int WC = BN / 4;
    constexpr int NT = WC / 16;
    constexpr int NH = NT / 2;

    __shared__ alignas(16) unsigned short lds_a[2][2][256 * 32]; // 64 KB
    __shared__ alignas(16) unsigned short lds_b[2][2][BN * 32];  // 64 KB

    const int tid  = threadIdx.x;
    const int lane = tid & 63;
    const int wave = tid >> 6;
    const int quad = lane >> 4;
    const int l16  = lane & 15;
    const int wm = wave >> 2;
    const int wn = wave & 3;

    const int nwg = gridDim.x * gridDim.y * gridDim.z;
    int lin = blockIdx.x + gridDim.x * (blockIdx.y + gridDim.y * blockIdx.z);
    if ((nwg & 7) == 0) lin = (lin & 7) * (nwg >> 3) + (lin >> 3);
    const int bx = lin % gridDim.x;
    const int byz = lin / gridDim.x;
    const int by = byz % gridDim.y;
    const int bz = byz / gridDim.y;

    const int tile_m = by * 256;
    const int tile_n = bx * BN;
    const int batch  = bz;

    const unsigned short* Ab = A + (size_t)batch * sA;
    const unsigned short* Bb = B + (size_t)batch * sB;

    const int srow = tid >> 2;
    const int scs  = ((tid & 3) ^ ((tid & 32) ? 2 : 0)) * 8;
    const unsigned short* gA = Ab + (size_t)(tile_m + srow) * K + scs;
    const unsigned short* gB = Bb + (size_t)(tile_n + srow) * K + scs;
    const int ldst = tid * 8;

    const int kcs   = (quad * 8) ^ ((l16 & 8) << 1);
    const int abase = (wm * 128 + l16) * 32 + kcs;
    const int bbase = (wn * WC  + l16) * 32 + kcs;

    floatx4 acc[8][NT];
    const floatx4 zero = {0.f, 0.f, 0.f, 0.f};
#pragma unroll
    for (int i = 0; i < 8; i++)
#pragma unroll
        for (int j = 0; j < NT; j++) acc[i][j] = zero;

    auto stageA = [&](int buf, int h, int k0) {
        const unsigned short* s = gA + (size_t)h * 128 * K + k0;
        gl_lds16(s,      &lds_a[buf][0][h * 4096 + ldst]);
        gl_lds16(s + 32, &lds_a[buf][1][h * 4096 + ldst]);
    };
    auto stageB = [&](int buf, int h, int k0) {
        const unsigned short* s = gB + (size_t)h * 128 * K + k0;
        gl_lds16(s,      &lds_b[buf][0][h * 4096 + ldst]);
        gl_lds16(s + 32, &lds_b[buf][1][h * 4096 + ldst]);
    };

    const int nt = K >> 6;

    stageA(0, 0, 0); stageA(0, 1, 0);
    stageB(0, 0, 0); stageB(0, 1, 0);
    if (nt > 1) {
        stageB(1, 0, 64); stageB(1, 1, 64);
        asm volatile("s_waitcnt vmcnt(4)" ::: "memory");
    } else {
        asm volatile("s_waitcnt vmcnt(0)" ::: "memory");
    }
    __builtin_amdgcn_s_barrier(); CFENCE;

    int cur = 0;
    for (int t = 0; t < nt; ++t) {
        const int k0 = t * 64;
        short8 afr[4][2], bfrA[NH][2], bfrB[NH][2];

        // ========== P1: read A0 + B0 ; stage A(t+1, lo) ==========
#pragma unroll
        for (int i = 0; i < 4; i++)
#pragma unroll
            for (int kh = 0; kh < 2; kh++)
                afr[i][kh] = *(const short8*)&lds_a[cur][kh][abase + i * 512];
#pragma unroll
        for (int j = 0; j < NH; j++)
#pragma unroll
            for (int kh = 0; kh < 2; kh++)
                bfrA[j][kh] = *(const short8*)&lds_b[cur][kh][bbase + j * 512];
        if (t + 1 < nt) stageA(cur ^ 1, 0, k0 + 64);
        CFENCE; __builtin_amdgcn_s_barrier(); CFENCE;
        __builtin_amdgcn_s_setprio(1);
#pragma unroll
        for (int i = 0; i < 4; i++)
#pragma unroll
            for (int j = 0; j < NH; j++)
#pragma unroll
                for (int kh = 0; kh < 2; kh++)
                    acc[i][j] = __builtin_amdgcn_mfma_f32_16x16x32_bf16(
                        bfrA[j][kh], afr[i][kh], acc[i][j], 0, 0, 0);
        __builtin_amdgcn_s_setprio(0);
        CFENCE; __builtin_amdgcn_s_barrier(); CFENCE;

        // ========== P2: read B1 ; stage A(t+1, hi) ==========
#pragma unroll
        for (int j = 0; j < NH; j++)
#pragma unroll
            for (int kh = 0; kh < 2; kh++)
                bfrB[j][kh] = *(const short8*)&lds_b[cur][kh][bbase + (NH + j) * 512];
        if (t + 1 < nt) stageA(cur ^ 1, 1, k0 + 64);
        CFENCE; __builtin_amdgcn_s_barrier(); CFENCE;
        __builtin_amdgcn_s_setprio(1);
#pragma unroll
        for (int i = 0; i < 4; i++)
#pragma unroll
            for (int j = 0; j < NH; j++)
#pragma unroll
                for (int kh = 0; kh < 2; kh++)
                    acc[i][NH + j] = __builtin_amdgcn_mfma_f32_16x16x32_bf16(
                        bfrB[j][kh], afr[i][kh], acc[i][NH + j], 0, 0, 0);
        __builtin_amdgcn_s_setprio(0);
        CFENCE; __builtin_amdgcn_s_barrier(); CFENCE;

        // ========== P3: read A1 ; stage B(t+2, lo) ==========
#pragma unroll
        for (int i = 0; i < 4; i++)
#pragma unroll
            for (int kh = 0; kh < 2; kh++)
                afr[i][kh] = *(const short8*)&lds_a[cur][kh][abase + (4 + i) * 512];
        if (t + 2 < nt) stageB(cur, 0, k0 + 128);
        CFENCE; __builtin_amdgcn_s_barrier(); CFENCE;
        __builtin_amdgcn_s_setprio(1);
#pragma unroll
        for (int i = 0; i < 4; i++)
#pragma unroll
            for (int j = 0; j < NH; j++)
#pragma unroll
                for (int kh = 0; kh < 2; kh++)
                    acc[4 + i][NH + j] = __builtin_amdgcn_mfma_f32_16x16x32_bf16(
                        bfrB[j][kh], afr[i][kh], acc[4 + i][NH + j], 0, 0, 0);
        __builtin_amdgcn_s_setprio(0);
        CFENCE; __builtin_amdgcn_s_barrier(); CFENCE;

        // ========== P4: stage B(t+2, hi) ; MFMA from regs ; boundary ======
        if (t + 2 < nt) stageB(cur, 1, k0 + 128);
        __builtin_amdgcn_s_setprio(1);
#pragma unroll
        for (int i = 0; i < 4; i++)
#pragma unroll
            for (int j = 0; j < NH; j++)
#pragma unroll
                for (int kh = 0; kh < 2; kh++)
                    acc[4 + i][j] = __builtin_amdgcn_mfma_f32_16x16x32_bf16(
                        bfrA[j][kh], afr[i][kh], acc[4 + i][j], 0, 0, 0);
        __builtin_amdgcn_s_setprio(0);
        if (t + 3 <= nt) {
            asm volatile("s_waitcnt vmcnt(4)" ::: "memory");
            __builtin_amdgcn_s_barrier(); CFENCE;
        } else if (t + 2 == nt) {
            asm volatile("s_waitcnt vmcnt(0)" ::: "memory");
            __builtin_amdgcn_s_barrier(); CFENCE;
        }
        cur ^= 1;
    }

    // ---- epilogue ----
#pragma unroll
    for (int i = 0; i < 8; i++) {
        const int row = tile_m + wm * 128 + i * 16 + l16;
#pragma unroll
        for (int j = 0; j < NT; j++) {
            const int colb = tile_n + wn * WC + j * 16 + quad * 4;
            float v[4];
#pragma unroll
            for (int r = 0; r < 4; r++) v[r] = acc[i][j][r];

            if (EPI == 3) {
                float4 mv = *(const float4*)&bias[(size_t)batch * sBias + colb];
                v[0] = v[0] * scale + mv.x;  v[1] = v[1] * scale + mv.y;
                v[2] = v[2] * scale + mv.z;  v[3] = v[3] * scale + mv.w;
            }
            if (EPI == 2) {
                float4 bv = *(const float4*)&bias[colb];
                v[0] += bv.x; v[1] += bv.y; v[2] += bv.z; v[3] += bv.w;
#pragma unroll
                for (int r = 0; r < 4; r++) v[r] = gelu_f(v[r]);
            }

            unsigned short* C = (unsigned short*)Cptr + (size_t)batch * sC;
            ushort4 h4;
            h4.x = f2bf(v[0]); h4.y = f2bf(v[1]);
            h4.z = f2bf(v[2]); h4.w = f2bf(v[3]);
            *(ushort4*)(C + (size_t)row * N + colb) = h4;
        }
    }
}

// ---------------------------------------------------------------------------
// gemm128 (r9): 128x128 bf16 MFMA GEMM, 256 threads = 4 waves (2M x 2N),
// per-wave out 64x64. LDS 64 KB -> 2 blocks/CU. Same verified levers:
// T1 XCD swizzle, T2 both-sides swizzle, 2-phase 16-MFMA clusters,
// counted vmcnt(4).
//  EPI: 4 = +resid (fp32 x), fp32 out (PV)
//       5 = +bias +resid (BF16 h — r10: LN1's fp32 h copy eliminated;
//           post-LN h is unit-scale so bf16's 0.4% rel err is negligible
//           vs the 3x absmax margin), fp32 out (FFN2)
//  M,N mult of 128; K mult of 128.
// ---------------------------------------------------------------------------
template<int EPI>
__global__ __launch_bounds__(256, 2) void gemm128(
    const unsigned short* __restrict__ A, const unsigned short* __restrict__ B,
    const float* __restrict__ bias, const void* __restrict__ residv,
    float* __restrict__ Cptr,
    int M, int N, int K, long sA, long sB, long sC, float scale)
{
    __shared__ alignas(16) unsigned short lds_a[2][2][128 * 32]; // 32 KB
    __shared__ alignas(16) unsigned short lds_b[2][2][128 * 32]; // 32 KB

    const int tid  = threadIdx.x;
    const int lane = tid & 63;
    const int wave = tid >> 6;         // 0..3
    const int quad = lane >> 4;
    const int l16  = lane & 15;
    const int wm = wave >> 1;          // 0..1 (64-row half)
    const int wn = wave & 1;           // 0..1 (64-col half)

    // T1 XCD swizzle
    const int nwg = gridDim.x * gridDim.y * gridDim.z;
    int lin = blockIdx.x + gridDim.x * (blockIdx.y + gridDim.y * blockIdx.z);
    if ((nwg & 7) == 0) lin = (lin & 7) * (nwg >> 3) + (lin >> 3);
    const int bx = lin % gridDim.x;
    const int byz = lin / gridDim.x;
    const int by = byz % gridDim.y;
    const int bz = byz / gridDim.y;

    const int tile_m = by * 128;
    const int tile_n = bx * 128;
    const int batch  = bz;

    const unsigned short* Ab = A + (size_t)batch * sA;
    const unsigned short* Bb = B + (size_t)batch * sB;

    const int srow = tid >> 2;                                  // 0..63
    const int scs  = ((tid & 3) ^ ((tid & 32) ? 2 : 0)) * 8;
    const unsigned short* gA = Ab + (size_t)(tile_m + srow) * K + scs;
    const unsigned short* gB = Bb + (size_t)(tile_n + srow) * K + scs;
    const int ldst = tid * 8;                                   // elems

    const int kcs   = (quad * 8) ^ ((l16 & 8) << 1);
    const int abase = (wm * 64 + l16) * 32 + kcs;
    const int bbase = (wn * 64 + l16) * 32 + kcs;

    floatx4 acc[4][4];
    const floatx4 zero = {0.f, 0.f, 0.f, 0.f};
#pragma unroll
    for (int i = 0; i < 4; i++)
#pragma unroll
        for (int j = 0; j < 4; j++) acc[i][j] = zero;

    auto stageA = [&](int buf, int k0) {
#pragma unroll
        for (int h = 0; h < 2; h++) {
            const unsigned short* s = gA + (size_t)h * 64 * K + k0;
            gl_lds16(s,      &lds_a[buf][0][h * 2048 + ldst]);
            gl_lds16(s + 32, &lds_a[buf][1][h * 2048 + ldst]);
        }
    };
    auto stageB = [&](int buf, int k0) {
#pragma unroll
        for (int h = 0; h < 2; h++) {
            const unsigned short* s = gB + (size_t)h * 64 * K + k0;
            gl_lds16(s,      &lds_b[buf][0][h * 2048 + ldst]);
            gl_lds16(s + 32, &lds_b[buf][1][h * 2048 + ldst]);
        }
    };

    const int nt = K >> 6;

    stageA(0, 0);
    stageB(0, 0);
    if (nt > 1) {
        stageB(1, 64);
        asm volatile("s_waitcnt vmcnt(4)" ::: "memory");
    } else {
        asm volatile("s_waitcnt vmcnt(0)" ::: "memory");
    }
    __builtin_amdgcn_s_barrier(); CFENCE;

    int cur = 0;
    for (int t = 0; t < nt; ++t) {
        const int k0 = t * 64;
        short8 afr[2][2], bfr[4][2];

        // ---- P1: read afr[0..1] + ALL bfr ; stage A(t+1) ----
#pragma unroll
        for (int i = 0; i < 2; i++)
#pragma unroll
            for (int kh = 0; kh < 2; kh++)
                afr[i][kh] = *(const short8*)&lds_a[cur][kh][abase + i * 512];
#pragma unroll
        for (int j = 0; j < 4; j++)
#pragma unroll
            for (int kh = 0; kh < 2; kh++)
                bfr[j][kh] = *(const short8*)&lds_b[cur][kh][bbase + j * 512];
        if (t + 1 < nt) stageA(cur ^ 1, k0 + 64);
        CFENCE; __builtin_amdgcn_s_barrier(); CFENCE;
        __builtin_amdgcn_s_setprio(1);
#pragma unroll
        for (int i = 0; i < 2; i++)
#pragma unroll
            for (int j = 0; j < 4; j++)
#pragma unroll
                for (int kh = 0; kh < 2; kh++)
                    acc[i][j] = __builtin_amdgcn_mfma_f32_16x16x32_bf16(
                        bfr[j][kh], afr[i][kh], acc[i][j], 0, 0, 0);
        __builtin_amdgcn_s_setprio(0);
        CFENCE; __builtin_amdgcn_s_barrier(); CFENCE;

        // ---- P2: read afr[2..3] ; stage B(t+2) over dead B[cur] ----
#pragma unroll
        for (int i = 0; i < 2; i++)
#pragma unroll
            for (int kh = 0; kh < 2; kh++)
                afr[i][kh] = *(const short8*)&lds_a[cur][kh][abase + (2 + i) * 512];
        if (t + 2 < nt) stageB(cur, k0 + 128);
        __builtin_amdgcn_s_setprio(1);
#pragma unroll
        for (int i = 0; i < 2; i++)
#pragma unroll
            for (int j = 0; j < 4; j++)
#pragma unroll
                for (int kh = 0; kh < 2; kh++)
                    acc[2 + i][j] = __builtin_amdgcn_mfma_f32_16x16x32_bf16(
                        bfr[j][kh], afr[i][kh], acc[2 + i][j], 0, 0, 0);
        __builtin_amdgcn_s_setprio(0);
        if (t + 3 <= nt) {
            asm volatile("s_waitcnt vmcnt(4)" ::: "memory");
            __builtin_amdgcn_s_barrier(); CFENCE;
        } else if (t + 2 == nt) {
            asm volatile("s_waitcnt vmcnt(0)" ::: "memory");
            __builtin_amdgcn_s_barrier(); CFENCE;
        }
        cur ^= 1;
    }

    // ---- epilogue: fp32 out, +resid (EPI4 fp32 / EPI5 bf16+bias) ----
#pragma unroll
    for (int i = 0; i < 4; i++) {
        const int row = tile_m + wm * 64 + i * 16 + l16;
#pragma unroll
        for (int j = 0; j < 4; j++) {
            const int colb = tile_n + wn * 64 + j * 16 + quad * 4;
            float v[4];
#pragma unroll
            for (int r = 0; r < 4; r++) v[r] = acc[i][j][r];

            if (EPI == 5) {
                float4 bv = *(const float4*)&bias[colb];
                v[0] += bv.x; v[1] += bv.y; v[2] += bv.z; v[3] += bv.w;
                const unsigned short* rb = (const unsigned short*)residv;
                ushort4 rv = *(const ushort4*)(rb + (size_t)batch * sC +
                                               (size_t)row * N + colb);
                v[0] += bf2f(rv.x); v[1] += bf2f(rv.y);
                v[2] += bf2f(rv.z); v[3] += bf2f(rv.w);
            }
            if (EPI == 4) {
                const float* rf = (const float*)residv;
                float4 rv = *(const float4*)(rf + (size_t)batch * sC +
                                             (size_t)row * N + colb);
                v[0] += rv.x; v[1] += rv.y; v[2] += rv.z; v[3] += rv.w;
            }

            float* C = Cptr + (size_t)batch * sC;
            float4 f4 = {v[0], v[1], v[2], v[3]};
            *(float4*)(C + (size_t)row * N + colb) = f4;
        }
    }
}

// ---------------------------------------------------------------------------
// x prep: read x [S,D] fp32 once -> xb [S,D] bf16 AND xTb [D,S] bf16.
// ---------------------------------------------------------------------------
__global__ __launch_bounds__(256) void x_prep_kernel(
    const float* __restrict__ in, unsigned short* __restrict__ straight,
    unsigned short* __restrict__ transposed, int R, int C, long sIn)
{
    __shared__ float tile[32][33];
    const int tc = blockIdx.x * 32, tr = blockIdx.y * 32;
    const float* src = in + (size_t)blockIdx.z * sIn;
    unsigned short* dstS = straight   + (size_t)blockIdx.z * sIn;
    unsigned short* dstT = transposed + (size_t)blockIdx.z * sIn;
    const int tx = threadIdx.x & 31, ty = threadIdx.x >> 5;
#pragma unroll
    for (int i = 0; i < 4; i++) {
        float val = src[(size_t)(tr + ty + i * 8) * C + tc + tx];
        tile[ty + i * 8][tx] = val;
        dstS[(size_t)(tr + ty + i * 8) * C + tc + tx] = f2bf(val);
    }
    __syncthreads();
#pragma unroll
    for (int i = 0; i < 4; i++)
        dstT[(size_t)(tc + ty + i * 8) * R + tr + tx] = f2bf(tile[tx][ty + i * 8]);
}

// ---------------------------------------------------------------------------
__global__ __launch_bounds__(256) void transpose_cvt_kernel(
    const float* __restrict__ in, unsigned short* __restrict__ out, int R, int C)
{
    __shared__ float tile[32][33];
    const int tc = blockIdx.x * 32, tr = blockIdx.y * 32;
    const int tx = threadIdx.x & 31, ty = threadIdx.x >> 5;
#pragma unroll
    for (int i = 0; i < 4; i++)
        tile[ty + i * 8][tx] = in[(size_t)(tr + ty + i * 8) * C + tc + tx];
    __syncthreads();
#pragma unroll
    for (int i = 0; i < 4; i++)
        out[(size_t)(tc + ty + i * 8) * R + tr + tx] = f2bf(tile[tx][ty + i * 8]);
}

// ---------------------------------------------------------------------------
// Pure row softmax over S=2048: bf16 in (scale+mask pre-applied) -> bf16 out.
// ---------------------------------------------------------------------------
__global__ __launch_bounds__(256) void softmax_bf16_kernel(
    const unsigned short* __restrict__ scores, unsigned short* __restrict__ probs,
    int S)
{
    __shared__ float red[4];
    const int row = blockIdx.x;
    const unsigned short* p = scores + (size_t)row * S;
    unsigned short* pr      = probs  + (size_t)row * S;
    const int tid  = threadIdx.x;
    const int lane = tid & 63;
    const int wav  = tid >> 6;

    uint4 raw = *(const uint4*)(p + tid * 8);   // 8 bf16
    float v[8];
    v[0] = __uint_as_float(raw.x << 16); v[1] = __uint_as_float(raw.x & 0xffff0000u);
    v[2] = __uint_as_float(raw.y << 16); v[3] = __uint_as_float(raw.y & 0xffff0000u);
    v[4] = __uint_as_float(raw.z << 16); v[5] = __uint_as_float(raw.z & 0xffff0000u);
    v[6] = __uint_as_float(raw.w << 16); v[7] = __uint_as_float(raw.w & 0xffff0000u);

    float mx = v[0];
#pragma unroll
    for (int k = 1; k < 8; k++) mx = fmaxf(mx, v[k]);
#pragma unroll
    for (int off = 32; off > 0; off >>= 1) mx = fmaxf(mx, __shfl_down(mx, off));
    if (lane == 0) red[wav] = mx;
    __syncthreads();
    mx = fmaxf(fmaxf(red[0], red[1]), fmaxf(red[2], red[3]));
    __syncthreads();

    float s = 0.f;
#pragma unroll
    for (int k = 0; k < 8; k++) { v[k] = __expf(v[k] - mx); s += v[k]; }
#pragma unroll
    for (int off = 32; off > 0; off >>= 1) s += __shfl_down(s, off);
    if (lane == 0) red[wav] = s;
    __syncthreads();
    s = red[0] + red[1] + red[2] + red[3];
    float inv = 1.0f / s;

    uint4 o;
    o.x = (unsigned)f2bf(v[0] * inv) | ((unsigned)f2bf(v[1] * inv) << 16);
    o.y = (unsigned)f2bf(v[2] * inv) | ((unsigned)f2bf(v[3] * inv) << 16);
    o.z = (unsigned)f2bf(v[4] * inv) | ((unsigned)f2bf(v[5] * inv) << 16);
    o.w = (unsigned)f2bf(v[6] * inv) | ((unsigned)f2bf(v[7] * inv) << 16);
    *(uint4*)(pr + tid * 8) = o;
}

// ---------------------------------------------------------------------------
// out_row = LayerNorm(X_row)*g + b.  D = 1024.
// MODE 0: write fp32 out (in-place safe).  MODE 1: write ONLY bf16 out16
// (r10 — drops LN1's fp32 h copy; FFN2 consumes the bf16 h as residual).
// ---------------------------------------------------------------------------
template<int MODE>
__global__ __launch_bounds__(256) void ln_kernel(
    const float* __restrict__ X,
    const float* __restrict__ g, const float* __restrict__ bta,
    float* __restrict__ out, unsigned short* __restrict__ out16, int D)
{
    __shared__ float red[8];
    const int row = blockIdx.x;
    const float* x = X + (size_t)row * D;
    const int tid  = threadIdx.x;
    const int lane = tid & 63;
    const int wav  = tid >> 6;

    float4 a = *(const float4*)(x + tid * 4);
    float v0 = a.x, v1 = a.y, v2 = a.z, v3 = a.w;

    float s1 = v0 + v1 + v2 + v3;
    float s2 = v0 * v0 + v1 * v1 + v2 * v2 + v3 * v3;
#pragma unroll
    for (int off = 32; off > 0; off >>= 1) {
        s1 += __shfl_down(s1, off);
        s2 += __shfl_down(s2, off);
    }
    if (lane == 0) { red[wav] = s1; red[4 + wav] = s2; }
    __syncthreads();
    s1 = red[0] + red[1] + red[2] + red[3];
    s2 = red[4] + red[5] + red[6] + red[7];
    const float mu  = s1 / (float)D;
    const float var = s2 / (float)D - mu * mu;
    const float rs  = rsqrtf(var + LN_EPS);

    float4 gg = *(const float4*)(g + tid * 4);
    float4 bb = *(const float4*)(bta + tid * 4);
    float4 r;
    r.x = (v0 - mu) * rs * gg.x + bb.x;
    r.y = (v1 - mu) * rs * gg.y + bb.y;
    r.z = (v2 - mu) * rs * gg.z + bb.z;
    r.w = (v3 - mu) * rs * gg.w + bb.w;
    if (MODE == 0) {
        *(float4*)(out + (size_t)row * D + tid * 4) = r;
    } else {
        ushort4 h;
        h.x = f2bf(r.x); h.y = f2bf(r.y); h.z = f2bf(r.z); h.w = f2bf(r.w);
        *(ushort4*)(out16 + (size_t)row * D + tid * 4) = h;
    }
}

// ---------------------------------------------------------------------------
extern "C" void kernel_launch(void* const* d_in, const int* in_sizes, int n_in,
                              void* d_out, int out_size, void* d_ws, size_t ws_size,
                              hipStream_t stream) {
    (void)in_sizes; (void)n_in; (void)out_size; (void)ws_size;
    const float* x    = (const float*)d_in[0];
    const float* mask = (const float*)d_in[1];
    const float* w1   = (const float*)d_in[2];
    const float* b1   = (const float*)d_in[3];
    const float* w2   = (const float*)d_in[4];
    const float* b2   = (const float*)d_in[5];
    const float* ln1g = (const float*)d_in[6];
    const float* ln1b = (const float*)d_in[7];
    const float* ln2g = (const float*)d_in[8];
    const float* ln2b = (const float*)d_in[9];
    float* out = (float*)d_out;

    const int B = 4, S = 2048, D = 1024, DFF = 4096;
    const size_t MB = 1024 * 1024;

    // ws (128 MiB):
    //  [0,32M):   scoresb bf16 (1-2)         } act bf16 [0,64M) (5-6)
    //  [32,64M):  xb bf16 [32,48M) (prep-1), then probs bf16 (2-3)
    //  [64,96M):  hbuf fp32 = x+attn, pre-LN (3-4)
    //  [96,112M): hb16 bf16 = LN1(hbuf) (4-6; FFN1 input AND FFN2 residual)
    //  [112,120M): w1T   [120,128M): w2T
    // d_out (32 MiB): xTb [0,16M) (prep-3); then fsum fp32 = h+ffn (6-7), LN in place.
    char* ws = (char*)d_ws;
    unsigned short* scoresb = (unsigned short*)ws;
    unsigned short* act     = (unsigned short*)ws;
    unsigned short* xb      = (unsigned short*)(ws + 32 * MB);
    unsigned short* probs   = (unsigned short*)(ws + 32 * MB);
    float*          hbuf    = (float*)(ws + 64 * MB);
    unsigned short* hb16    = (unsigned short*)(ws + 96 * MB);
    unsigned short* w1T     = (unsigned short*)(ws + 112 * MB);
    unsigned short* w2T     = (unsigned short*)(ws + 120 * MB);
    unsigned short* xTb     = (unsigned short*)d_out;
    float*          fsum    = (float*)d_out;

    // --- prep ---
    x_prep_kernel<<<dim3(D / 32, S / 32, B), 256, 0, stream>>>(
        x, xb, xTb, S, D, (long)S * D);
    transpose_cvt_kernel<<<dim3(DFF / 32, D / 32, 1), 256, 0, stream>>>(w1, w1T, D, DFF);
    transpose_cvt_kernel<<<dim3(D / 32, DFF / 32, 1), 256, 0, stream>>>(w2, w2T, DFF, D);

    // 1. scoresb[b] = (xb[b] @ xb[b]^T)*scale + mask  -> bf16   (256 blocks)
    hipLaunchKernelGGL((gemm8p<3, 256>), dim3(S / 256, S / 256, B), dim3(512), 0, stream,
                       xb, xb, mask, (const float*)nullptr, (void*)scoresb,
                       S, S, D, (long)S * D, (long)S * D, (long)S * S, (long)S, 0.03125f);
    // 2. probs = softmax(scoresb) -> bf16
    softmax_bf16_kernel<<<B * S, 256, 0, stream>>>(scoresb, probs, S);
    // 3. hbuf[b] = x[b] + probs[b] @ xTb[b]^T  -> fp32 (pre-LN)
    hipLaunchKernelGGL((gemm128<4>), dim3(D / 128, S / 128, B), dim3(256), 0, stream,
                       probs, xTb, (const float*)nullptr, (const void*)x, hbuf,
                       S, D, S, (long)S * S, (long)D * S, (long)S * D, 0.f);
    // 4. hb16 = LN(hbuf) -> bf16 ONLY (r10: fp32 h copy eliminated)
    hipLaunchKernelGGL((ln_kernel<1>), dim3(B * S), dim3(256), 0, stream,
                       hbuf, ln1g, ln1b, (float*)nullptr, hb16, D);
    // 5. act = gelu(h @ w1 + b1) -> bf16                        (512 blocks)
    hipLaunchKernelGGL((gemm8p<2, 256>), dim3(DFF / 256, (B * S) / 256, 1), dim3(512), 0, stream,
                       hb16, w1T, b1, (const float*)nullptr, (void*)act,
                       B * S, DFF, D, 0L, 0L, 0L, 0L, 0.f);
    // 6. fsum = h(bf16) + act @ w2 + b2 -> fp32 (into d_out)
    hipLaunchKernelGGL((gemm128<5>), dim3(D / 128, (B * S) / 128, 1), dim3(256), 0, stream,
                       act, w2T, b2, (const void*)hb16, fsum,
                       B * S, D, DFF, 0L, 0L, (long)0, 0.f);
    // 7. out = LN(fsum) in place
    hipLaunchKernelGGL((ln_kernel<0>), dim3(B * S), dim3(256), 0, stream,
                       fsum, ln2g, ln2b, out, (unsigned short*)nullptr, D);
}

// Round 11
// 395.913 us; speedup vs baseline: 1.0321x; 1.0132x over previous
//
#include <hip/hip_runtime.h>
#include <hip/hip_bf16.h>
#include <math.h>

#define LN_EPS 1e-5f

typedef short short8 __attribute__((ext_vector_type(8)));
typedef float floatx4 __attribute__((ext_vector_type(4)));

__device__ inline unsigned short f2bf(float f) {
    unsigned int u = __float_as_uint(f);
    u += 0x7fff + ((u >> 16) & 1);   // round-to-nearest-even
    return (unsigned short)(u >> 16);
}

__device__ inline float bf2f(unsigned short h) {
    return __uint_as_float((unsigned)h << 16);
}

__device__ inline void gl_lds16(const unsigned short* g, unsigned short* l) {
    __builtin_amdgcn_global_load_lds(
        (__attribute__((address_space(1))) const void*)g,
        (__attribute__((address_space(3))) void*)l, 16, 0, 0);
}

// overflow-safe tanh-approx GELU (max abs err ~1e-3 vs exact)
__device__ inline float gelu_f(float v) {
    float u2 = 2.0f * v * (0.7978845608f + 0.0356774081f * v * v);
    float t  = 1.0f - 2.0f / (__expf(u2) + 1.0f);
    return 0.5f * v * (1.0f + t);
}

#define CFENCE asm volatile("" ::: "memory")

// ---------------------------------------------------------------------------
// gemm8p: 256x256 bf16 MFMA GEMM — r4/r8 configuration (FFN1 93 µs, 739 TF =
// 87% of shape-matched m248 reference; QK^T). TEXTUALLY FROZEN since r8 —
// rule #19: changing this kernel's instantiation set re-rolled its codegen
// at -45% once (r7). BN=128 work lives in gemm128 (adding that kernel did
// NOT perturb FFN1 — r9/r10 measured 93-95).
//  T1 XCD swizzle, T2 both-sides st_16x32, counted vmcnt(4), T5 setprio.
//  4 phases/K-tile, 16-MFMA clusters.
//  EPI: 2 = +bias, GELU, bf16 out;  3 = *scale + mask, bf16 out.
// ---------------------------------------------------------------------------
template<int EPI, int BN>
__global__ __launch_bounds__(512, 2) void gemm8p(
    const unsigned short* __restrict__ A, const unsigned short* __restrict__ B,
    const float* __restrict__ bias, const float* __restrict__ resid,
    void* __restrict__ Cptr,
    int M, int N, int K, long sA, long sB, long sC, long sBias, float scale)
{
    static_assert(BN == 256, "gemm8p: BN==256 only (BN=128 -> gemm128)");
    constexpr int WC = BN / 4;
    constexpr int NT = WC / 16;
    constexpr int NH = NT / 2;

    __shared__ alignas(16) unsigned short lds_a[2][2][256 * 32]; // 64 KB
    __shared__ alignas(16) unsigned short lds_b[2][2][BN * 32];  // 64 KB

    const int tid  = threadIdx.x;
    const int lane = tid & 63;
    const int wave = tid >> 6;
    const int quad = lane >> 4;
    const int l16  = lane & 15;
    const int wm = wave >> 2;
    const int wn = wave & 3;

    const int nwg = gridDim.x * gridDim.y * gridDim.z;
    int lin = blockIdx.x + gridDim.x * (blockIdx.y + gridDim.y * blockIdx.z);
    if ((nwg & 7) == 0) lin = (lin & 7) * (nwg >> 3) + (lin >> 3);
    const int bx = lin % gridDim.x;
    const int byz = lin / gridDim.x;
    const int by = byz % gridDim.y;
    const int bz = byz / gridDim.y;

    const int tile_m = by * 256;
    const int tile_n = bx * BN;
    const int batch  = bz;

    const unsigned short* Ab = A + (size_t)batch * sA;
    const unsigned short* Bb = B + (size_t)batch * sB;

    const int srow = tid >> 2;
    const int scs  = ((tid & 3) ^ ((tid & 32) ? 2 : 0)) * 8;
    const unsigned short* gA = Ab + (size_t)(tile_m + srow) * K + scs;
    const unsigned short* gB = Bb + (size_t)(tile_n + srow) * K + scs;
    const int ldst = tid * 8;

    const int kcs   = (quad * 8) ^ ((l16 & 8) << 1);
    const int abase = (wm * 128 + l16) * 32 + kcs;
    const int bbase = (wn * WC  + l16) * 32 + kcs;

    floatx4 acc[8][NT];
    const floatx4 zero = {0.f, 0.f, 0.f, 0.f};
#pragma unroll
    for (int i = 0; i < 8; i++)
#pragma unroll
        for (int j = 0; j < NT; j++) acc[i][j] = zero;

    auto stageA = [&](int buf, int h, int k0) {
        const unsigned short* s = gA + (size_t)h * 128 * K + k0;
        gl_lds16(s,      &lds_a[buf][0][h * 4096 + ldst]);
        gl_lds16(s + 32, &lds_a[buf][1][h * 4096 + ldst]);
    };
    auto stageB = [&](int buf, int h, int k0) {
        const unsigned short* s = gB + (size_t)h * 128 * K + k0;
        gl_lds16(s,      &lds_b[buf][0][h * 4096 + ldst]);
        gl_lds16(s + 32, &lds_b[buf][1][h * 4096 + ldst]);
    };

    const int nt = K >> 6;

    stageA(0, 0, 0); stageA(0, 1, 0);
    stageB(0, 0, 0); stageB(0, 1, 0);
    if (nt > 1) {
        stageB(1, 0, 64); stageB(1, 1, 64);
        asm volatile("s_waitcnt vmcnt(4)" ::: "memory");
    } else {
        asm volatile("s_waitcnt vmcnt(0)" ::: "memory");
    }
    __builtin_amdgcn_s_barrier(); CFENCE;

    int cur = 0;
    for (int t = 0; t < nt; ++t) {
        const int k0 = t * 64;
        short8 afr[4][2], bfrA[NH][2], bfrB[NH][2];

        // ========== P1: read A0 + B0 ; stage A(t+1, lo) ==========
#pragma unroll
        for (int i = 0; i < 4; i++)
#pragma unroll
            for (int kh = 0; kh < 2; kh++)
                afr[i][kh] = *(const short8*)&lds_a[cur][kh][abase + i * 512];
#pragma unroll
        for (int j = 0; j < NH; j++)
#pragma unroll
            for (int kh = 0; kh < 2; kh++)
                bfrA[j][kh] = *(const short8*)&lds_b[cur][kh][bbase + j * 512];
        if (t + 1 < nt) stageA(cur ^ 1, 0, k0 + 64);
        CFENCE; __builtin_amdgcn_s_barrier(); CFENCE;
        __builtin_amdgcn_s_setprio(1);
#pragma unroll
        for (int i = 0; i < 4; i++)
#pragma unroll
            for (int j = 0; j < NH; j++)
#pragma unroll
                for (int kh = 0; kh < 2; kh++)
                    acc[i][j] = __builtin_amdgcn_mfma_f32_16x16x32_bf16(
                        bfrA[j][kh], afr[i][kh], acc[i][j], 0, 0, 0);
        __builtin_amdgcn_s_setprio(0);
        CFENCE; __builtin_amdgcn_s_barrier(); CFENCE;

        // ========== P2: read B1 ; stage A(t+1, hi) ==========
#pragma unroll
        for (int j = 0; j < NH; j++)
#pragma unroll
            for (int kh = 0; kh < 2; kh++)
                bfrB[j][kh] = *(const short8*)&lds_b[cur][kh][bbase + (NH + j) * 512];
        if (t + 1 < nt) stageA(cur ^ 1, 1, k0 + 64);
        CFENCE; __builtin_amdgcn_s_barrier(); CFENCE;
        __builtin_amdgcn_s_setprio(1);
#pragma unroll
        for (int i = 0; i < 4; i++)
#pragma unroll
            for (int j = 0; j < NH; j++)
#pragma unroll
                for (int kh = 0; kh < 2; kh++)
                    acc[i][NH + j] = __builtin_amdgcn_mfma_f32_16x16x32_bf16(
                        bfrB[j][kh], afr[i][kh], acc[i][NH + j], 0, 0, 0);
        __builtin_amdgcn_s_setprio(0);
        CFENCE; __builtin_amdgcn_s_barrier(); CFENCE;

        // ========== P3: read A1 ; stage B(t+2, lo) ==========
#pragma unroll
        for (int i = 0; i < 4; i++)
#pragma unroll
            for (int kh = 0; kh < 2; kh++)
                afr[i][kh] = *(const short8*)&lds_a[cur][kh][abase + (4 + i) * 512];
        if (t + 2 < nt) stageB(cur, 0, k0 + 128);
        CFENCE; __builtin_amdgcn_s_barrier(); CFENCE;
        __builtin_amdgcn_s_setprio(1);
#pragma unroll
        for (int i = 0; i < 4; i++)
#pragma unroll
            for (int j = 0; j < NH; j++)
#pragma unroll
                for (int kh = 0; kh < 2; kh++)
                    acc[4 + i][NH + j] = __builtin_amdgcn_mfma_f32_16x16x32_bf16(
                        bfrB[j][kh], afr[i][kh], acc[4 + i][NH + j], 0, 0, 0);
        __builtin_amdgcn_s_setprio(0);
        CFENCE; __builtin_amdgcn_s_barrier(); CFENCE;

        // ========== P4: stage B(t+2, hi) ; MFMA from regs ; boundary ======
        if (t + 2 < nt) stageB(cur, 1, k0 + 128);
        __builtin_amdgcn_s_setprio(1);
#pragma unroll
        for (int i = 0; i < 4; i++)
#pragma unroll
            for (int j = 0; j < NH; j++)
#pragma unroll
                for (int kh = 0; kh < 2; kh++)
                    acc[4 + i][j] = __builtin_amdgcn_mfma_f32_16x16x32_bf16(
                        bfrA[j][kh], afr[i][kh], acc[4 + i][j], 0, 0, 0);
        __builtin_amdgcn_s_setprio(0);
        if (t + 3 <= nt) {
            asm volatile("s_waitcnt vmcnt(4)" ::: "memory");
            __builtin_amdgcn_s_barrier(); CFENCE;
        } else if (t + 2 == nt) {
            asm volatile("s_waitcnt vmcnt(0)" ::: "memory");
            __builtin_amdgcn_s_barrier(); CFENCE;
        }
        cur ^= 1;
    }

    // ---- epilogue ----
#pragma unroll
    for (int i = 0; i < 8; i++) {
        const int row = tile_m + wm * 128 + i * 16 + l16;
#pragma unroll
        for (int j = 0; j < NT; j++) {
            const int colb = tile_n + wn * WC + j * 16 + quad * 4;
            float v[4];
#pragma unroll
            for (int r = 0; r < 4; r++) v[r] = acc[i][j][r];

            if (EPI == 3) {
                float4 mv = *(const float4*)&bias[(size_t)batch * sBias + colb];
                v[0] = v[0] * scale + mv.x;  v[1] = v[1] * scale + mv.y;
                v[2] = v[2] * scale + mv.z;  v[3] = v[3] * scale + mv.w;
            }
            if (EPI == 2) {
                float4 bv = *(const float4*)&bias[colb];
                v[0] += bv.x; v[1] += bv.y; v[2] += bv.z; v[3] += bv.w;
#pragma unroll
                for (int r = 0; r < 4; r++) v[r] = gelu_f(v[r]);
            }

            unsigned short* C = (unsigned short*)Cptr + (size_t)batch * sC;
            ushort4 h4;
            h4.x = f2bf(v[0]); h4.y = f2bf(v[1]);
            h4.z = f2bf(v[2]); h4.w = f2bf(v[3]);
            *(ushort4*)(C + (size_t)row * N + colb) = h4;
        }
    }
}

// ---------------------------------------------------------------------------
// gemm128 (r9): 128x128 bf16 MFMA GEMM, 256 threads = 4 waves (2M x 2N),
// per-wave out 64x64. LDS 64 KB -> 2 blocks/CU. T1 XCD swizzle, T2
// both-sides swizzle, 2-phase 16-MFMA clusters, counted vmcnt(4).
//  r11: all residuals AND outputs bf16 — every consumer is a LayerNorm,
//  which renormalizes; bf16's 0.4% rel err ~ 0.004 absolute post-LN vs
//  a 3x absmax margin. Saves 83.5 MB of fp32 traffic across PV/FFN2/LNs.
//  EPI: 4 = +resid, bf16 out (PV: x + attn, pre-LN1)
//       5 = +bias +resid, bf16 out (FFN2: h + ffn, pre-LN2)
//  M,N mult of 128; K mult of 128.
// ---------------------------------------------------------------------------
template<int EPI>
__global__ __launch_bounds__(256, 2) void gemm128(
    const unsigned short* __restrict__ A, const unsigned short* __restrict__ B,
    const float* __restrict__ bias, const unsigned short* __restrict__ resid,
    unsigned short* __restrict__ Cptr,
    int M, int N, int K, long sA, long sB, long sC, float scale)
{
    __shared__ alignas(16) unsigned short lds_a[2][2][128 * 32]; // 32 KB
    __shared__ alignas(16) unsigned short lds_b[2][2][128 * 32]; // 32 KB

    const int tid  = threadIdx.x;
    const int lane = tid & 63;
    const int wave = tid >> 6;         // 0..3
    const int quad = lane >> 4;
    const int l16  = lane & 15;
    const int wm = wave >> 1;          // 0..1 (64-row half)
    const int wn = wave & 1;           // 0..1 (64-col half)

    // T1 XCD swizzle
    const int nwg = gridDim.x * gridDim.y * gridDim.z;
    int lin = blockIdx.x + gridDim.x * (blockIdx.y + gridDim.y * blockIdx.z);
    if ((nwg & 7) == 0) lin = (lin & 7) * (nwg >> 3) + (lin >> 3);
    const int bx = lin % gridDim.x;
    const int byz = lin / gridDim.x;
    const int by = byz % gridDim.y;
    const int bz = byz / gridDim.y;

    const int tile_m = by * 128;
    const int tile_n = bx * 128;
    const int batch  = bz;

    const unsigned short* Ab = A + (size_t)batch * sA;
    const unsigned short* Bb = B + (size_t)batch * sB;

    const int srow = tid >> 2;                                  // 0..63
    const int scs  = ((tid & 3) ^ ((tid & 32) ? 2 : 0)) * 8;
    const unsigned short* gA = Ab + (size_t)(tile_m + srow) * K + scs;
    const unsigned short* gB = Bb + (size_t)(tile_n + srow) * K + scs;
    const int ldst = tid * 8;                                   // elems

    const int kcs   = (quad * 8) ^ ((l16 & 8) << 1);
    const int abase = (wm * 64 + l16) * 32 + kcs;
    const int bbase = (wn * 64 + l16) * 32 + kcs;

    floatx4 acc[4][4];
    const floatx4 zero = {0.f, 0.f, 0.f, 0.f};
#pragma unroll
    for (int i = 0; i < 4; i++)
#pragma unroll
        for (int j = 0; j < 4; j++) acc[i][j] = zero;

    auto stageA = [&](int buf, int k0) {
#pragma unroll
        for (int h = 0; h < 2; h++) {
            const unsigned short* s = gA + (size_t)h * 64 * K + k0;
            gl_lds16(s,      &lds_a[buf][0][h * 2048 + ldst]);
            gl_lds16(s + 32, &lds_a[buf][1][h * 2048 + ldst]);
        }
    };
    auto stageB = [&](int buf, int k0) {
#pragma unroll
        for (int h = 0; h < 2; h++) {
            const unsigned short* s = gB + (size_t)h * 64 * K + k0;
            gl_lds16(s,      &lds_b[buf][0][h * 2048 + ldst]);
            gl_lds16(s + 32, &lds_b[buf][1][h * 2048 + ldst]);
        }
    };

    const int nt = K >> 6;

    stageA(0, 0);
    stageB(0, 0);
    if (nt > 1) {
        stageB(1, 64);
        asm volatile("s_waitcnt vmcnt(4)" ::: "memory");
    } else {
        asm volatile("s_waitcnt vmcnt(0)" ::: "memory");
    }
    __builtin_amdgcn_s_barrier(); CFENCE;

    int cur = 0;
    for (int t = 0; t < nt; ++t) {
        const int k0 = t * 64;
        short8 afr[2][2], bfr[4][2];

        // ---- P1: read afr[0..1] + ALL bfr ; stage A(t+1) ----
#pragma unroll
        for (int i = 0; i < 2; i++)
#pragma unroll
            for (int kh = 0; kh < 2; kh++)
                afr[i][kh] = *(const short8*)&lds_a[cur][kh][abase + i * 512];
#pragma unroll
        for (int j = 0; j < 4; j++)
#pragma unroll
            for (int kh = 0; kh < 2; kh++)
                bfr[j][kh] = *(const short8*)&lds_b[cur][kh][bbase + j * 512];
        if (t + 1 < nt) stageA(cur ^ 1, k0 + 64);
        CFENCE; __builtin_amdgcn_s_barrier(); CFENCE;
        __builtin_amdgcn_s_setprio(1);
#pragma unroll
        for (int i = 0; i < 2; i++)
#pragma unroll
            for (int j = 0; j < 4; j++)
#pragma unroll
                for (int kh = 0; kh < 2; kh++)
                    acc[i][j] = __builtin_amdgcn_mfma_f32_16x16x32_bf16(
                        bfr[j][kh], afr[i][kh], acc[i][j], 0, 0, 0);
        __builtin_amdgcn_s_setprio(0);
        // end-P1 barrier: all waves' B reads complete -> B[cur] dead
        CFENCE; __builtin_amdgcn_s_barrier(); CFENCE;

        // ---- P2: read afr[2..3] ; stage B(t+2) over dead B[cur] ----
#pragma unroll
        for (int i = 0; i < 2; i++)
#pragma unroll
            for (int kh = 0; kh < 2; kh++)
                afr[i][kh] = *(const short8*)&lds_a[cur][kh][abase + (2 + i) * 512];
        if (t + 2 < nt) stageB(cur, k0 + 128);
        __builtin_amdgcn_s_setprio(1);
#pragma unroll
        for (int i = 0; i < 2; i++)
#pragma unroll
            for (int j = 0; j < 4; j++)
#pragma unroll
                for (int kh = 0; kh < 2; kh++)
                    acc[2 + i][j] = __builtin_amdgcn_mfma_f32_16x16x32_bf16(
                        bfr[j][kh], afr[i][kh], acc[2 + i][j], 0, 0, 0);
        __builtin_amdgcn_s_setprio(0);
        if (t + 3 <= nt) {
            asm volatile("s_waitcnt vmcnt(4)" ::: "memory");
            __builtin_amdgcn_s_barrier(); CFENCE;
        } else if (t + 2 == nt) {
            asm volatile("s_waitcnt vmcnt(0)" ::: "memory");
            __builtin_amdgcn_s_barrier(); CFENCE;
        }
        cur ^= 1;
    }

    // ---- epilogue: +bias(EPI5) + bf16 resid ; bf16 out ----
#pragma unroll
    for (int i = 0; i < 4; i++) {
        const int row = tile_m + wm * 64 + i * 16 + l16;
#pragma unroll
        for (int j = 0; j < 4; j++) {
            const int colb = tile_n + wn * 64 + j * 16 + quad * 4;
            float v[4];
#pragma unroll
            for (int r = 0; r < 4; r++) v[r] = acc[i][j][r];

            if (EPI == 5) {
                float4 bv = *(const float4*)&bias[colb];
                v[0] += bv.x; v[1] += bv.y; v[2] += bv.z; v[3] += bv.w;
            }
            ushort4 rv = *(const ushort4*)(resid + (size_t)batch * sC +
                                           (size_t)row * N + colb);
            v[0] += bf2f(rv.x); v[1] += bf2f(rv.y);
            v[2] += bf2f(rv.z); v[3] += bf2f(rv.w);

            unsigned short* C = Cptr + (size_t)batch * sC;
            ushort4 h4;
            h4.x = f2bf(v[0]); h4.y = f2bf(v[1]);
            h4.z = f2bf(v[2]); h4.w = f2bf(v[3]);
            *(ushort4*)(C + (size_t)row * N + colb) = h4;
        }
    }
}

// ---------------------------------------------------------------------------
// x prep: read x [S,D] fp32 once -> xb [S,D] bf16 AND xTb [D,S] bf16.
// ---------------------------------------------------------------------------
__global__ __launch_bounds__(256) void x_prep_kernel(
    const float* __restrict__ in, unsigned short* __restrict__ straight,
    unsigned short* __restrict__ transposed, int R, int C, long sIn)
{
    __shared__ float tile[32][33];
    const int tc = blockIdx.x * 32, tr = blockIdx.y * 32;
    const float* src = in + (size_t)blockIdx.z * sIn;
    unsigned short* dstS = straight   + (size_t)blockIdx.z * sIn;
    unsigned short* dstT = transposed + (size_t)blockIdx.z * sIn;
    const int tx = threadIdx.x & 31, ty = threadIdx.x >> 5;
#pragma unroll
    for (int i = 0; i < 4; i++) {
        float val = src[(size_t)(tr + ty + i * 8) * C + tc + tx];
        tile[ty + i * 8][tx] = val;
        dstS[(size_t)(tr + ty + i * 8) * C + tc + tx] = f2bf(val);
    }
    __syncthreads();
#pragma unroll
    for (int i = 0; i < 4; i++)
        dstT[(size_t)(tc + ty + i * 8) * R + tr + tx] = f2bf(tile[tx][ty + i * 8]);
}

// ---------------------------------------------------------------------------
__global__ __launch_bounds__(256) void transpose_cvt_kernel(
    const float* __restrict__ in, unsigned short* __restrict__ out, int R, int C)
{
    __shared__ float tile[32][33];
    const int tc = blockIdx.x * 32, tr = blockIdx.y * 32;
    const int tx = threadIdx.x & 31, ty = threadIdx.x >> 5;
#pragma unroll
    for (int i = 0; i < 4; i++)
        tile[ty + i * 8][tx] = in[(size_t)(tr + ty + i * 8) * C + tc + tx];
    __syncthreads();
#pragma unroll
    for (int i = 0; i < 4; i++)
        out[(size_t)(tc + ty + i * 8) * R + tr + tx] = f2bf(tile[tx][ty + i * 8]);
}

// ---------------------------------------------------------------------------
// Pure row softmax over S=2048: bf16 in (scale+mask pre-applied) -> bf16 out.
// ---------------------------------------------------------------------------
__global__ __launch_bounds__(256) void softmax_bf16_kernel(
    const unsigned short* __restrict__ scores, unsigned short* __restrict__ probs,
    int S)
{
    __shared__ float red[4];
    const int row = blockIdx.x;
    const unsigned short* p = scores + (size_t)row * S;
    unsigned short* pr      = probs  + (size_t)row * S;
    const int tid  = threadIdx.x;
    const int lane = tid & 63;
    const int wav  = tid >> 6;

    uint4 raw = *(const uint4*)(p + tid * 8);   // 8 bf16
    float v[8];
    v[0] = __uint_as_float(raw.x << 16); v[1] = __uint_as_float(raw.x & 0xffff0000u);
    v[2] = __uint_as_float(raw.y << 16); v[3] = __uint_as_float(raw.y & 0xffff0000u);
    v[4] = __uint_as_float(raw.z << 16); v[5] = __uint_as_float(raw.z & 0xffff0000u);
    v[6] = __uint_as_float(raw.w << 16); v[7] = __uint_as_float(raw.w & 0xffff0000u);

    float mx = v[0];
#pragma unroll
    for (int k = 1; k < 8; k++) mx = fmaxf(mx, v[k]);
#pragma unroll
    for (int off = 32; off > 0; off >>= 1) mx = fmaxf(mx, __shfl_down(mx, off));
    if (lane == 0) red[wav] = mx;
    __syncthreads();
    mx = fmaxf(fmaxf(red[0], red[1]), fmaxf(red[2], red[3]));
    __syncthreads();

    float s = 0.f;
#pragma unroll
    for (int k = 0; k < 8; k++) { v[k] = __expf(v[k] - mx); s += v[k]; }
#pragma unroll
    for (int off = 32; off > 0; off >>= 1) s += __shfl_down(s, off);
    if (lane == 0) red[wav] = s;
    __syncthreads();
    s = red[0] + red[1] + red[2] + red[3];
    float inv = 1.0f / s;

    uint4 o;
    o.x = (unsigned)f2bf(v[0] * inv) | ((unsigned)f2bf(v[1] * inv) << 16);
    o.y = (unsigned)f2bf(v[2] * inv) | ((unsigned)f2bf(v[3] * inv) << 16);
    o.z = (unsigned)f2bf(v[4] * inv) | ((unsigned)f2bf(v[5] * inv) << 16);
    o.w = (unsigned)f2bf(v[6] * inv) | ((unsigned)f2bf(v[7] * inv) << 16);
    *(uint4*)(pr + tid * 8) = o;
}

// ---------------------------------------------------------------------------
// out_row = LayerNorm(X_row)*g + b.  D = 1024.  INPUT IS BF16 (r11).
// fp32 math throughout; OUT_BF16 selects bf16 (LN1) or fp32 (LN2) output.
// ---------------------------------------------------------------------------
template<int OUT_BF16>
__global__ __launch_bounds__(256) void ln_kernel(
    const unsigned short* __restrict__ X,
    const float* __restrict__ g, const float* __restrict__ bta,
    float* __restrict__ out, unsigned short* __restrict__ out16, int D)
{
    __shared__ float red[8];
    const int row = blockIdx.x;
    const unsigned short* x = X + (size_t)row * D;
    const int tid  = threadIdx.x;
    const int lane = tid & 63;
    const int wav  = tid >> 6;

    ushort4 a = *(const ushort4*)(x + tid * 4);
    float v0 = bf2f(a.x), v1 = bf2f(a.y), v2 = bf2f(a.z), v3 = bf2f(a.w);

    float s1 = v0 + v1 + v2 + v3;
    float s2 = v0 * v0 + v1 * v1 + v2 * v2 + v3 * v3;
#pragma unroll
    for (int off = 32; off > 0; off >>= 1) {
        s1 += __shfl_down(s1, off);
        s2 += __shfl_down(s2, off);
    }
    if (lane == 0) { red[wav] = s1; red[4 + wav] = s2; }
    __syncthreads();
    s1 = red[0] + red[1] + red[2] + red[3];
    s2 = red[4] + red[5] + red[6] + red[7];
    const float mu  = s1 / (float)D;
    const float var = s2 / (float)D - mu * mu;
    const float rs  = rsqrtf(var + LN_EPS);

    float4 gg = *(const float4*)(g + tid * 4);
    float4 bb = *(const float4*)(bta + tid * 4);
    float4 r;
    r.x = (v0 - mu) * rs * gg.x + bb.x;
    r.y = (v1 - mu) * rs * gg.y + bb.y;
    r.z = (v2 - mu) * rs * gg.z + bb.z;
    r.w = (v3 - mu) * rs * gg.w + bb.w;
    if (OUT_BF16) {
        ushort4 h;
        h.x = f2bf(r.x); h.y = f2bf(r.y); h.z = f2bf(r.z); h.w = f2bf(r.w);
        *(ushort4*)(out16 + (size_t)row * D + tid * 4) = h;
    } else {
        *(float4*)(out + (size_t)row * D + tid * 4) = r;
    }
}

// ---------------------------------------------------------------------------
extern "C" void kernel_launch(void* const* d_in, const int* in_sizes, int n_in,
                              void* d_out, int out_size, void* d_ws, size_t ws_size,
                              hipStream_t stream) {
    (void)in_sizes; (void)n_in; (void)out_size; (void)ws_size;
    const float* x    = (const float*)d_in[0];
    const float* mask = (const float*)d_in[1];
    const float* w1   = (const float*)d_in[2];
    const float* b1   = (const float*)d_in[3];
    const float* w2   = (const float*)d_in[4];
    const float* b2   = (const float*)d_in[5];
    const float* ln1g = (const float*)d_in[6];
    const float* ln1b = (const float*)d_in[7];
    const float* ln2g = (const float*)d_in[8];
    const float* ln2b = (const float*)d_in[9];
    float* out = (float*)d_out;

    const int B = 4, S = 2048, D = 1024, DFF = 4096;
    const size_t MB = 1024 * 1024;

    // ws (256 MiB):
    //  [0,32M):    scoresb bf16 (1-2)   } act bf16 [0,64M) (5-6)
    //  [32,48M):   xb bf16 (prep-3: QK^T input AND PV residual)
    //  [64,80M):   hpre16 bf16 = x+attn, pre-LN1 (3-4)
    //  [80,96M):   fsum16 bf16 = h+ffn, pre-LN2 (6-7)
    //  [96,112M):  hb16 bf16 = LN1 out (4-6: FFN1 input AND FFN2 residual)
    //  [112,120M): w1T   [120,128M): w2T
    //  [128,160M): probs bf16 (2-3)  (moved here r11 so xb survives)
    // d_out (32 MiB): xTb [0,16M) (prep-3); final fp32 out (7).
    char* ws = (char*)d_ws;
    unsigned short* scoresb = (unsigned short*)ws;
    unsigned short* act     = (unsigned short*)ws;
    unsigned short* xb      = (unsigned short*)(ws + 32 * MB);
    unsigned short* hpre16  = (unsigned short*)(ws + 64 * MB);
    unsigned short* fsum16  = (unsigned short*)(ws + 80 * MB);
    unsigned short* hb16    = (unsigned short*)(ws + 96 * MB);
    unsigned short* w1T     = (unsigned short*)(ws + 112 * MB);
    unsigned short* w2T     = (unsigned short*)(ws + 120 * MB);
    unsigned short* probs   = (unsigned short*)(ws + 128 * MB);
    unsigned short* xTb     = (unsigned short*)d_out;

    // --- prep ---
    x_prep_kernel<<<dim3(D / 32, S / 32, B), 256, 0, stream>>>(
        x, xb, xTb, S, D, (long)S * D);
    transpose_cvt_kernel<<<dim3(DFF / 32, D / 32, 1), 256, 0, stream>>>(w1, w1T, D, DFF);
    transpose_cvt_kernel<<<dim3(D / 32, DFF / 32, 1), 256, 0, stream>>>(w2, w2T, DFF, D);

    // 1. scoresb[b] = (xb[b] @ xb[b]^T)*scale + mask  -> bf16   (256 blocks)
    hipLaunchKernelGGL((gemm8p<3, 256>), dim3(S / 256, S / 256, B), dim3(512), 0, stream,
                       xb, xb, mask, (const float*)nullptr, (void*)scoresb,
                       S, S, D, (long)S * D, (long)S * D, (long)S * S, (long)S, 0.03125f);
    // 2. probs = softmax(scoresb) -> bf16 (at ws+128M; xb stays live)
    softmax_bf16_kernel<<<B * S, 256, 0, stream>>>(scoresb, probs, S);
    // 3. hpre16[b] = xb[b] + probs[b] @ xTb[b]^T  -> bf16
    hipLaunchKernelGGL((gemm128<4>), dim3(D / 128, S / 128, B), dim3(256), 0, stream,
                       probs, xTb, (const float*)nullptr, xb, hpre16,
                       S, D, S, (long)S * S, (long)D * S, (long)S * D, 0.f);
    // 4. hb16 = LN(hpre16) -> bf16
    hipLaunchKernelGGL((ln_kernel<1>), dim3(B * S), dim3(256), 0, stream,
                       hpre16, ln1g, ln1b, (float*)nullptr, hb16, D);
    // 5. act = gelu(h @ w1 + b1) -> bf16                        (512 blocks)
    hipLaunchKernelGGL((gemm8p<2, 256>), dim3(DFF / 256, (B * S) / 256, 1), dim3(512), 0, stream,
                       hb16, w1T, b1, (const float*)nullptr, (void*)act,
                       B * S, DFF, D, 0L, 0L, 0L, 0L, 0.f);
    // 6. fsum16 = h(bf16) + act @ w2 + b2 -> bf16
    hipLaunchKernelGGL((gemm128<5>), dim3(D / 128, (B * S) / 128, 1), dim3(256), 0, stream,
                       act, w2T, b2, hb16, fsum16,
                       B * S, D, DFF, 0L, 0L, (long)0, 0.f);
    // 7. out = LN(fsum16) -> fp32 (d_out)
    hipLaunchKernelGGL((ln_kernel<0>), dim3(B * S), dim3(256), 0, stream,
                       fsum16, ln2g, ln2b, out, (unsigned short*)nullptr, D);
}